// Round 9
// baseline (306.421 us; speedup 1.0000x reference)
//
#include <hip/hip_runtime.h>
#include <hip/hip_bf16.h>

#define EPSV 1e-5f

typedef __attribute__((ext_vector_type(8))) short bf16x8;
typedef __attribute__((ext_vector_type(16))) float f32x16;

static __device__ __forceinline__ short f2bf(float f) {
    __hip_bfloat16 b = __float2bfloat16(f);
    return __builtin_bit_cast(short, b);
}
static __device__ __forceinline__ float bf2f(short s) {
    unsigned u = ((unsigned)(unsigned short)s) << 16;
    return __builtin_bit_cast(float, u);
}

typedef __attribute__((address_space(3))) void lds_t;
typedef const __attribute__((address_space(1))) void gbl_t;
static __device__ __forceinline__ void glds16(const void* g, void* l) {
    __builtin_amdgcn_global_load_lds((gbl_t*)g, (lds_t*)l, 16, 0, 0);
}

template <int N_>
static __device__ __forceinline__ void wait_vmcnt() {
    if constexpr (N_ == 0)      asm volatile("s_waitcnt vmcnt(0)" ::: "memory");
    else if constexpr (N_ == 1) asm volatile("s_waitcnt vmcnt(1)" ::: "memory");
    else if constexpr (N_ == 2) asm volatile("s_waitcnt vmcnt(2)" ::: "memory");
    else if constexpr (N_ == 4) asm volatile("s_waitcnt vmcnt(4)" ::: "memory");
}

// Fused role-split: blocks [0,EBL) = edge MLP; blocks [EBL, EBL+65) = w2->w2a repack
// (one h-slab per block, LDS-transposed so both read AND write are coalesced).
// w2a slab layout: [(c*2+rowg)*512 + l*8 + j] = bf16(w2[h][i*64+o]),
//   o = rowg*32+(l&31), i = c*16+(l>>5)*8+j ; slab 64 = b2.
// zge[e*64 + h] = bf16(relu(b1[h] + ea@w1))
template <int CIN>
__global__ void k_edge_prep(const float* __restrict__ ea, const float* __restrict__ w1,
                            const float* __restrict__ b1, short* __restrict__ zge, int E, int EBL,
                            const float* __restrict__ w2, const float* __restrict__ b2,
                            short* __restrict__ w2a) {
    constexpr int CH = CIN / 16;
    int t = threadIdx.x;
    if ((int)blockIdx.x >= EBL) {
        int h = (int)blockIdx.x - EBL;          // 0..64
        __shared__ float sW[CIN][65];
        const float* srcp = (h < 64) ? (w2 + (size_t)h * (CIN * 64)) : b2;
        for (int f = t; f < CIN * 64; f += 256) sW[f >> 6][f & 63] = srcp[f];
        __syncthreads();
        int l = t & 63, w = t >> 6;
        short* outp = w2a + (size_t)h * (CH * 1024);
        constexpr int SEGW = (CH * 2) / 4 > 0 ? (CH * 2) / 4 : 1;   // segs per wave
        #pragma unroll
        for (int q = 0; q < SEGW; ++q) {
            int s = w + q * 4;
            int c = s >> 1, rowg = s & 1;
            int ib = c * 16 + (l >> 5) * 8;
            int o = rowg * 32 + (l & 31);
            union { bf16x8 v; short sh[8]; } ov;
            #pragma unroll
            for (int j = 0; j < 8; ++j) ov.sh[j] = f2bf(sW[ib + j][o]);
            *reinterpret_cast<bf16x8*>(outp + s * 512 + l * 8) = ov.v;
        }
        return;
    }
    __shared__ float sEA[64][17];
    int e0 = blockIdx.x * 64;
    for (int f = t; f < 64 * 16; f += 256) {
        int e = f >> 4, i = f & 15;
        int ge = e0 + e;
        sEA[e][i] = (ge < E) ? ea[(size_t)ge * 16 + i] : 0.f;
    }
    __syncthreads();
    int lane = t & 63, w = t >> 6;
    int ge = e0 + lane;
    union { bf16x8 v[2]; short s[16]; } ov;
    #pragma unroll
    for (int hh = 0; hh < 16; ++hh) {
        int h = w * 16 + hh;
        float acc = b1[h];
        #pragma unroll
        for (int i = 0; i < 16; ++i) acc += sEA[lane][i] * w1[i * 64 + h];
        ov.s[hh] = f2bf(fmaxf(acc, 0.f));
    }
    if (ge < E) {
        short* base = zge + (size_t)ge * 64 + w * 16;
        *reinterpret_cast<bf16x8*>(base) = ov.v[0];
        *reinterpret_cast<bf16x8*>(base + 8) = ov.v[1];
    }
}

// layer-1 fused prep: agg init (root GEMM on x) + x -> bf16
__global__ void k_pre1(const float* __restrict__ x, const float* __restrict__ root,
                       const float* __restrict__ bias, short* __restrict__ xb,
                       float* __restrict__ out, int N) {
    int idx = blockIdx.x * blockDim.x + threadIdx.x;
    int n = idx >> 6, o = idx & 63;
    if (n >= N) return;
    float acc = bias[o];
    #pragma unroll
    for (int i = 0; i < 32; ++i) acc += x[(size_t)n * 32 + i] * root[i * 64 + o];
    out[(size_t)n * 64 + o] = acc;
    if (o < 32) xb[(size_t)n * 32 + o] = f2bf(x[(size_t)n * 32 + o]);
}

// MFMA msg v7: counted-vmcnt software pipeline (T3/T4).
// 4 x 1-slab LDS buffers; stage slab ci+2 each iter; s_waitcnt vmcnt(2*ROUNDS) keeps
// 2 slabs in flight across raw s_barrier (never drains to 0 in main loop).
// z in padded LDS (overlaid on sT) -> no scratch (rule #20 fix).
template <int CIN>
__global__ __launch_bounds__(256, 3) void k_msg(const short* __restrict__ zge,
                                                const short* __restrict__ xb,
                                                const int* __restrict__ src,
                                                const int* __restrict__ dstv,
                                                const short* __restrict__ w2a,
                                                float* __restrict__ agg, int E) {
    constexpr int CH = CIN / 16;
    constexpr int SLAB = CH * 1024;        // shorts per h-slab
    constexpr int ROUNDS = CH / 2;         // glds rounds per slab per thread (2 or 1)
    __shared__ short sA[4 * SLAB] __attribute__((aligned(16)));
    __shared__ float sT[64][66];           // epilogue transpose; overlaid by sZ in main loop
    short* sZ = reinterpret_cast<short*>(&sT[0][0]);   // [64][66] shorts (pad: conflict-free)

    int t = threadIdx.x;
    int e0 = blockIdx.x * 64;
    int lane = t & 63, w = t >> 6;
    int rowg = w >> 1;            // o half
    int colg = w & 1;             // e half
    int kg = lane >> 5, l31 = lane & 31;
    int ecol = colg * 32 + l31;
    int ge = e0 + ecol;
    int gec = min(ge, E - 1);

    auto stage = [&](int buf, int slab) {
        const short* g = w2a + (size_t)slab * SLAB;
        short* l0 = sA + buf * SLAB;
        #pragma unroll
        for (int r = 0; r < ROUNDS; ++r) {
            int off = r * 2048 + w * 512;
            glds16(g + off + lane * 8, l0 + off);
        }
    };

    stage(0, 0);
    stage(1, 1);

    // B operand: x[src(e)] fragments, fixed across all h
    int srow = src[gec];
    bf16x8 xB[CH];
    #pragma unroll
    for (int c = 0; c < CH; ++c)
        xB[c] = *reinterpret_cast<const bf16x8*>(xb + (size_t)srow * CIN + c * 16 + kg * 8);

    // z tile -> LDS (padded rows of 66 shorts)
    #pragma unroll
    for (int rr = 0; rr < 2; ++rr) {
        int f = rr * 256 + t;              // f < 512 : e = f>>3, seg = f&7
        int e = f >> 3, seg = f & 7;
        int gz = min(e0 + e, E - 1);
        bf16x8 zv = *reinterpret_cast<const bf16x8*>(zge + (size_t)gz * 64 + seg * 8);
        *reinterpret_cast<bf16x8*>(sZ + e * 66 + seg * 8) = zv;
    }

    f32x16 zero;
    #pragma unroll
    for (int r = 0; r < 16; ++r) zero[r] = 0.f;
    asm volatile("" : "+v"(zero));

    f32x16 acc = zero;

    __syncthreads();   // drains ALL prologue vmem (slabs 0,1 + xB + z) -> in-loop vmcnt counts staging only

    #pragma unroll 1
    for (int ci = 0; ci < 65; ++ci) {
        if (ci + 2 <= 64) stage((ci + 2) & 3, ci + 2);
        if (ci < 63)      wait_vmcnt<2 * ROUNDS>();   // slab ci retired; ci+1, ci+2 stay in flight
        else if (ci == 63) wait_vmcnt<ROUNDS>();
        else               wait_vmcnt<0>();
        __builtin_amdgcn_sched_barrier(0);
        __builtin_amdgcn_s_barrier();
        __builtin_amdgcn_sched_barrier(0);

        const short* base = sA + (ci & 3) * SLAB;
        bf16x8 a0[CH];
        #pragma unroll
        for (int c = 0; c < CH; ++c)
            a0[c] = *reinterpret_cast<const bf16x8*>(base + (c * 2 + rowg) * 512 + lane * 8);
        f32x16 t0 = __builtin_amdgcn_mfma_f32_32x32x16_bf16(a0[0], xB[0], zero, 0, 0, 0);
        #pragma unroll
        for (int c = 1; c < CH; ++c)
            t0 = __builtin_amdgcn_mfma_f32_32x32x16_bf16(a0[c], xB[c], t0, 0, 0, 0);

        if (ci < 64) {
            float zf = bf2f(sZ[ecol * 66 + ci]);
            #pragma unroll
            for (int r = 0; r < 16; ++r) acc[r] = fmaf(zf, t0[r], acc[r]);
        } else {       // b2 slab: z = 1
            #pragma unroll
            for (int r = 0; r < 16; ++r) acc[r] += t0[r];
        }
    }

    __syncthreads();   // all sZ reads done before sT overwrite (staging fully drained at ci=64)

    // transpose via LDS: each wave writes a disjoint 32x32 quadrant
    #pragma unroll
    for (int r = 0; r < 16; ++r) {
        int o = (r & 3) + 8 * (r >> 2) + 4 * kg + 32 * rowg;
        sT[o][ecol] = acc[r];
    }
    __syncthreads();

    // coalesced scatter: 64 lanes = 64 consecutive o for one edge
    for (int e = w; e < 64; e += 4) {
        int geo = e0 + e;
        if (geo < E) {
            int d = dstv[geo];
            atomicAdd(&agg[(size_t)d * 64 + lane], sT[lane][e]);
        }
    }
}

// fused LayerNorm+ReLU -> bf16 (for next msg) AND next layer's root GEMM (agg init).
__global__ void k_ln_root(const float* __restrict__ hin, const float* __restrict__ g,
                          const float* __restrict__ b, const float* __restrict__ root,
                          const float* __restrict__ bias, short* __restrict__ xbout,
                          float* __restrict__ aggnext, int N) {
    __shared__ float sh[4][64];
    int w = threadIdx.x >> 6, lane = threadIdx.x & 63;
    int n = blockIdx.x * 4 + w;
    bool valid = n < N;
    int nc = valid ? n : (N - 1);
    float v = hin[(size_t)nc * 64 + lane];
    float s = v;
    #pragma unroll
    for (int d = 32; d > 0; d >>= 1) s += __shfl_xor(s, d, 64);
    float mean = s * (1.f / 64.f);
    float dv = v - mean;
    float s2 = dv * dv;
    #pragma unroll
    for (int d = 32; d > 0; d >>= 1) s2 += __shfl_xor(s2, d, 64);
    float var = s2 * (1.f / 64.f);
    float o = fmaxf(dv * rsqrtf(var + EPSV) * g[lane] + b[lane], 0.f);
    if (valid) xbout[(size_t)n * 64 + lane] = f2bf(o);
    sh[w][lane] = o;
    __syncthreads();
    float acc = bias[lane];
    #pragma unroll 8
    for (int i = 0; i < 64; ++i) acc = fmaf(sh[w][i], root[i * 64 + lane], acc);
    if (valid) aggnext[(size_t)n * 64 + lane] = acc;
}

// plain LayerNorm+ReLU in place (final layer)
__global__ void k_ln(float* __restrict__ h, const float* __restrict__ g, const float* __restrict__ b, int N) {
    int n = blockIdx.x * 4 + (threadIdx.x >> 6);
    int lane = threadIdx.x & 63;
    if (n >= N) return;
    float v = h[(size_t)n * 64 + lane];
    float s = v;
    #pragma unroll
    for (int d = 32; d > 0; d >>= 1) s += __shfl_xor(s, d, 64);
    float mean = s * (1.f / 64.f);
    float dv = v - mean;
    float s2 = dv * dv;
    #pragma unroll
    for (int d = 32; d > 0; d >>= 1) s2 += __shfl_xor(s2, d, 64);
    float var = s2 * (1.f / 64.f);
    h[(size_t)n * 64 + lane] = fmaxf(dv * rsqrtf(var + EPSV) * g[lane] + b[lane], 0.f);
}

// fused mean-pool (binary search on sorted batch) + MLP head; 4 waves/graph
__global__ void k_pool_head(const float* __restrict__ h, const int* __restrict__ batch,
                            const float* __restrict__ fc1w, const float* __restrict__ fc1b,
                            const float* __restrict__ fc2w, const float* __restrict__ fc2b,
                            float* __restrict__ out, int N) {
    __shared__ float part[4][64];
    __shared__ float sh[64];
    __shared__ float sh2[32];
    int g = blockIdx.x;
    int t = threadIdx.x, lane = t & 63, w = t >> 6;
    int lo = 0, hi = N;
    while (lo < hi) { int m = (lo + hi) >> 1; if (batch[m] < g) lo = m + 1; else hi = m; }
    int s0 = lo;
    hi = N;
    while (lo < hi) { int m = (lo + hi) >> 1; if (batch[m] < g + 1) lo = m + 1; else hi = m; }
    int s1 = lo;
    float s = 0.f;
    for (int n = s0 + w; n < s1; n += 4) s += h[(size_t)n * 64 + lane];
    part[w][lane] = s;
    __syncthreads();
    if (t < 64) {
        float c = fmaxf((float)(s1 - s0), 1.f);
        sh[t] = (part[0][t] + part[1][t] + part[2][t] + part[3][t]) / c;
    }
    __syncthreads();
    if (t < 32) {
        float a = fc1b[t];
        #pragma unroll
        for (int o = 0; o < 64; ++o) a += sh[o] * fc1w[o * 32 + t];
        sh2[t] = fmaxf(a, 0.f);
    }
    __syncthreads();
    if (t == 0) {
        float a = fc2b[0];
        #pragma unroll
        for (int j = 0; j < 32; ++j) a += sh2[j] * fc2w[j];
        out[g] = a;
    }
}

extern "C" void kernel_launch(void* const* d_in, const int* in_sizes, int n_in,
                              void* d_out, int out_size, void* d_ws, size_t ws_size,
                              hipStream_t stream) {
    const float* x     = (const float*)d_in[0];
    const int*   ei    = (const int*)d_in[1];
    const float* ea    = (const float*)d_in[2];
    const int*   batch = (const int*)d_in[3];
    int E = in_sizes[1] / 2;
    int N = in_sizes[3];
    int G = out_size;  // DOUT = 1
    const int* src  = ei;
    const int* dstv = ei + E;

    const float* P[24];
    for (int i = 0; i < 24; ++i) P[i] = (const float*)d_in[4 + i];
    const float* fc1w = (const float*)d_in[28];
    const float* fc1b = (const float*)d_in[29];
    const float* fc2w = (const float*)d_in[30];
    const float* fc2b = (const float*)d_in[31];

    // workspace layout
    float* hA  = (float*)d_ws;                 // N*64 f32
    float* hB  = hA + (size_t)N * 64;          // N*64 f32
    short* zge = (short*)(hB + (size_t)N * 64);// E*64 bf16 (z rows)
    short* xbA = zge + (size_t)E * 64;         // N*64 bf16
    short* xbB = xbA + (size_t)N * 64;         // N*64 bf16
    short* w2a = xbB + (size_t)N * 64;         // 65 slabs * CH*1024 bf16

    int ebl = (E + 63) / 64;
    int n64 = (N * 64 + 255) / 256;
    int nln = (N + 3) / 4;

    // ---- layer 1 (cin = 32) ----
    k_edge_prep<32><<<ebl + 65, 256, 0, stream>>>(ea, P[0], P[1], zge, E, ebl, P[2], P[3], w2a);
    k_pre1<<<n64, 256, 0, stream>>>(x, P[4], P[5], xbA, hA, N);
    k_msg<32><<<ebl, 256, 0, stream>>>(zge, xbA, src, dstv, w2a, hA, E);

    // ---- layer 2 (cin = 64) ----
    k_edge_prep<64><<<ebl + 65, 256, 0, stream>>>(ea, P[8], P[9], zge, E, ebl, P[10], P[11], w2a);
    k_ln_root<<<nln, 256, 0, stream>>>(hA, P[6], P[7], P[12], P[13], xbB, hB, N);
    k_msg<64><<<ebl, 256, 0, stream>>>(zge, xbB, src, dstv, w2a, hB, E);

    // ---- layer 3 (cin = 64) ----
    k_edge_prep<64><<<ebl + 65, 256, 0, stream>>>(ea, P[16], P[17], zge, E, ebl, P[18], P[19], w2a);
    k_ln_root<<<nln, 256, 0, stream>>>(hB, P[14], P[15], P[20], P[21], xbA, hA, N);
    k_msg<64><<<ebl, 256, 0, stream>>>(zge, xbA, src, dstv, w2a, hA, E);
    k_ln<<<nln, 256, 0, stream>>>(hA, P[22], P[23], N);

    // ---- fused pool + head ----
    k_pool_head<<<G, 256, 0, stream>>>(hA, batch, fc1w, fc1b, fc2w, fc2b, (float*)d_out, N);
}